// Round 15
// baseline (359.422 us; speedup 1.0000x reference)
//
#include <hip/hip_runtime.h>
#include <hip/hip_bf16.h>
#include <math.h>

#define NN 50000
#define NE 800000
#define COUT 32
#define KK 10
#define HCOL 320           // K*OUT  (bf16 h panel width, row-major)
#define EPSV 1e-15f
#define SCAN_NB 196        // ceil(50000/256)
#define MBATCH 64          // msg edge batch per wave
#define NREP 4             // counter replicas
#define GEMM_NB 1563       // ceil(NN / 32)

typedef __attribute__((ext_vector_type(8))) short short8v;   // 8 bf16 (4 VGPR)
typedef __attribute__((ext_vector_type(4))) float f32x4;

__device__ __forceinline__ unsigned int bfpack(float a, float b) {
    // RNE f32->bf16 pair pack (matches __float2bfloat16 for finite values)
    unsigned int ua = __float_as_uint(a), ub = __float_as_uint(b);
    ua = (ua + 0x7fffu + ((ua >> 16) & 1u)) >> 16;
    ub = (ub + 0x7fffu + ((ub >> 16) & 1u)) >> 16;
    return ua | (ub << 16);
}

// ================= CSR build (once per call) =================
// standalone: random-RMW work must not co-run with anything (R13/R14 lessons)
__global__ __launch_bounds__(256) void rank_edges(const int* __restrict__ ei,
                                                  int* __restrict__ cntS,
                                                  int* __restrict__ cntD,
                                                  ushort2* __restrict__ rankL) {
    const int base = blockIdx.x * (NREP * 256);
    const int t = threadIdx.x;
#pragma unroll
    for (int i = 0; i < NREP; i++) {
        int e = base + i * 256 + t;
        if (e < NE) {
            int src = ei[e], dst = ei[NE + e];
            unsigned short rs = (unsigned short)atomicAdd(cntS + i * NN + src, 1);
            unsigned short rd = (unsigned short)atomicAdd(cntD + i * NN + dst, 1);
            rankL[e] = make_ushort2(rs, rd);
        }
    }
}

__device__ __forceinline__ int block_incl_scan(int v, int* s) {
    int t = threadIdx.x;
    s[t] = v; __syncthreads();
#pragma unroll
    for (int off = 1; off < 256; off <<= 1) {
        int u = (t >= off) ? s[t - off] : 0;
        __syncthreads();
        s[t] += u; __syncthreads();
    }
    int r = s[t]; __syncthreads();
    return r;
}

__global__ __launch_bounds__(256) void scan_partial(const int* __restrict__ cntS,
                                                    const int* __restrict__ cntD,
                                                    int* __restrict__ bsumS,
                                                    int* __restrict__ bsumD) {
    __shared__ int s[256];
    int i = blockIdx.x * 256 + threadIdx.x;
    int vs = 0, vd = 0;
    if (i < NN) {
#pragma unroll
        for (int r = 0; r < NREP; r++) {
            vs += cntS[(size_t)r * NN + i];
            vd += cntD[(size_t)r * NN + i];
        }
    }
    int is = block_incl_scan(vs, s);
    int id = block_incl_scan(vd, s);
    if (threadIdx.x == 255) { bsumS[blockIdx.x] = is; bsumD[blockIdx.x] = id; }
}

__global__ __launch_bounds__(256) void scan_blocks(int* __restrict__ bsumS,
                                                   int* __restrict__ bsumD,
                                                   int* __restrict__ bposS,
                                                   int* __restrict__ bposD) {
    __shared__ int s[256];
    int t = threadIdx.x;
    int vs = (t < SCAN_NB) ? bsumS[t] : 0;
    int vd = (t < SCAN_NB) ? bsumD[t] : 0;
    int is = block_incl_scan(vs, s);
    int id = block_incl_scan(vd, s);
    if (t < SCAN_NB) { bposS[t] = is - vs; bposD[t] = id - vd; }
}

__global__ __launch_bounds__(256) void scan_final(int* __restrict__ cntS,
                                                  int* __restrict__ cntD,
                                                  const int* __restrict__ bposS,
                                                  const int* __restrict__ bposD,
                                                  int* __restrict__ rpS,
                                                  int* __restrict__ rpD,
                                                  float* __restrict__ invdeg) {
    __shared__ int s[256];
    int i = blockIdx.x * 256 + threadIdx.x;
    int cs[NREP], cd[NREP];
    int vs = 0, vd = 0;
    if (i < NN) {
#pragma unroll
        for (int r = 0; r < NREP; r++) {
            cs[r] = cntS[(size_t)r * NN + i];
            cd[r] = cntD[(size_t)r * NN + i];
            vs += cs[r]; vd += cd[r];
        }
    }
    int is = block_incl_scan(vs, s);
    int id = block_incl_scan(vd, s);
    if (i < NN) {
        int es = bposS[blockIdx.x] + is - vs;
        int ed = bposD[blockIdx.x] + id - vd;
        rpS[i] = es; rpD[i] = ed;
        invdeg[i] = 1.0f / fmaxf((float)vd, 1.0f);
        int run = es;
#pragma unroll
        for (int r = 0; r < NREP; r++) { cntS[(size_t)r * NN + i] = run; run += cs[r]; }
        run = ed;
#pragma unroll
        for (int r = 0; r < NREP; r++) { cntD[(size_t)r * NN + i] = run; run += cd[r]; }
    }
    if (i == NN) { rpS[NN] = NE; rpD[NN] = NE; }
}

// atomic-free permutation scatter: one aligned 8B store per edge {dslot, bf16 ea pair}
__global__ void scatter_perm(const int* __restrict__ ei, const float* __restrict__ ea,
                             const ushort2* __restrict__ rankL,
                             const int* __restrict__ cntS, const int* __restrict__ cntD,
                             uint2* __restrict__ dperm) {
    int e = blockIdx.x * 256 + threadIdx.x;
    if (e >= NE) return;
    int src = ei[e], dst = ei[NE + e];
    int rep = (e >> 8) & (NREP - 1);        // matches rank_edges' slot layout
    ushort2 rl = rankL[e];
    int sslot = cntS[(size_t)rep * NN + src] + rl.x;
    int dslot = cntD[(size_t)rep * NN + dst] + rl.y;
    float2 a = ((const float2*)ea)[e];
    dperm[sslot] = make_uint2((unsigned int)dslot, bfpack(a.x, a.y));
}

// ================= per-layer kernels =================

// shared gemm body (32 nodes/block, 384 threads)
template <int CIN>
__device__ __forceinline__ void gemm_body(const float* __restrict__ x,
                                          const float* __restrict__ g,
                                          const float* __restrict__ root,
                                          __hip_bfloat16* __restrict__ hxh,
                                          float* __restrict__ hxr,
                                          float (*xs)[36], int bid, int tid) {
    const int n0 = bid * 32;
    for (int idx = tid; idx < 32 * CIN; idx += 384) {
        int i = idx / CIN, c = idx % CIN;
        int n = n0 + i;
        xs[c][i] = (n < NN) ? x[(size_t)n * CIN + c] : 0.0f;
    }
    __syncthreads();
    if (tid < 352) {
        const int jj = tid >> 2;            // col quad 0..87
        const int rr = tid & 3;             // row-group of 8
        const bool isg = (jj < 80);
        const float* w = isg ? (g + 4 * jj) : (root + 4 * (jj - 80));
        const int ws = isg ? HCOL : COUT;
        float acc[4][8];
#pragma unroll
        for (int cc = 0; cc < 4; cc++)
#pragma unroll
            for (int r = 0; r < 8; r++) acc[cc][r] = 0.0f;
        for (int c = 0; c < CIN; c++) {
            const float4 wv = *(const float4*)&w[(size_t)c * ws];
            const float4 x0 = *(const float4*)&xs[c][8 * rr];
            const float4 x1 = *(const float4*)&xs[c][8 * rr + 4];
            const float xr[8] = {x0.x, x0.y, x0.z, x0.w, x1.x, x1.y, x1.z, x1.w};
            const float wr[4] = {wv.x, wv.y, wv.z, wv.w};
#pragma unroll
            for (int cc = 0; cc < 4; cc++)
#pragma unroll
                for (int r = 0; r < 8; r++)
                    acc[cc][r] = fmaf(xr[r], wr[cc], acc[cc][r]);
        }
#pragma unroll
        for (int r = 0; r < 8; r++) {
            int n = n0 + 8 * rr + r;
            if (n < NN) {
                if (isg) {
                    unsigned int u01 = bfpack(acc[0][r], acc[1][r]);
                    unsigned int u23 = bfpack(acc[2][r], acc[3][r]);
                    *(uint2*)&hxh[(size_t)n * HCOL + 4 * jj] = make_uint2(u01, u23);
                } else {
                    *(float4*)&hxr[(size_t)n * COUT + 4 * (jj - 80)] =
                        make_float4(acc[0][r], acc[1][r], acc[2][r], acc[3][r]);
                }
            }
        }
    }
}

__global__ __launch_bounds__(384) void gemm_hx64(const float* __restrict__ x,
                                                 const float* __restrict__ g,
                                                 const float* __restrict__ root,
                                                 __hip_bfloat16* __restrict__ hxh,
                                                 float* __restrict__ hxr) {
    __shared__ float xs[64][36];
    gemm_body<64>(x, g, root, hxh, hxr, xs, blockIdx.x, threadIdx.x);
}

__global__ __launch_bounds__(384) void gemm_hx32(const float* __restrict__ x,
                                                 const float* __restrict__ g,
                                                 const float* __restrict__ root,
                                                 __hip_bfloat16* __restrict__ hxh,
                                                 float* __restrict__ hxr) {
    __shared__ float xs[32][36];
    gemm_body<32>(x, g, root, hxh, hxr, xs, blockIdx.x, threadIdx.x);
}

// Phase A (MFMA): per-src wave; phase1 one lane/edge -> 10 gaussians into LDS;
// phase2 16-edge x 32-out tiles via two mfma_f32_16x16x32_bf16.
// m-row layout is COLUMN-INTERLEAVED: uint slot j of a row holds cols (j, j+16)
// packed (lo,hi) -> each edge's 64B row is written as ONE full line by 16 lanes
// (1 random-line touch/edge instead of 2).
__global__ __launch_bounds__(256) void msg_kernel(const __hip_bfloat16* __restrict__ hxh,
                                                  const int* __restrict__ rpS,
                                                  const uint2* __restrict__ dperm,
                                                  const float* __restrict__ mu,
                                                  const float* __restrict__ sigma,
                                                  unsigned int* __restrict__ m) {
    __shared__ unsigned int gws[4][MBATCH][8];   // 8 KB: [wave][edge][16 khat bf16]
    __shared__ int dposs[4][MBATCH];             // 1 KB
    float muk[2 * KK], isgm[2 * KK];
#pragma unroll
    for (int k = 0; k < 2 * KK; k++) {
        muk[k] = mu[k];
        float sv = sigma[k];
        isgm[k] = 1.0f / (EPSV + sv * sv);
    }
    const int tid = threadIdx.x;
    const int wave = tid >> 6, lane = tid & 63;
    const int o16 = lane & 15, q = lane >> 4;
    const int nwaves = gridDim.x * 4;
    const f32x4 zacc = {0.0f, 0.0f, 0.0f, 0.0f};
    for (int n = blockIdx.x * 4 + wave; n < NN; n += nwaves) {
        const int s0 = rpS[n], s1 = rpS[n + 1];
        if (s0 == s1) continue;
        short8v B0 = {0, 0, 0, 0, 0, 0, 0, 0};
        short8v B1 = {0, 0, 0, 0, 0, 0, 0, 0};
        if (q < 2) {                         // khat 0..15 live; 16..31 zero
            const short* hr = (const short*)(hxh + (size_t)n * HCOL);
#pragma unroll
            for (int i = 0; i < 8; i++) {
                int k = q * 8 + i;
                int kc = (k < KK) ? k : (KK - 1);     // clamped (in-bounds) address
                short v0 = hr[kc * 32 + o16];
                short v1 = hr[kc * 32 + 16 + o16];
                B0[i] = (k < KK) ? v0 : (short)0;
                B1[i] = (k < KK) ? v1 : (short)0;
            }
        }
        for (int base = s0; base < s1; base += MBATCH) {
            const int cnt = min(MBATCH, s1 - base);
            uint4 ua = make_uint4(0u, 0u, 0u, 0u);
            unsigned int ub = 0u; int dp = 0;
            if (lane < cnt) {                // phase 1: one edge per lane
                uint2 qv = dperm[base + lane];
                float ax = __uint_as_float(qv.y << 16);
                float ay = __uint_as_float(qv.y & 0xffff0000u);
                float wv[KK];
#pragma unroll
                for (int k = 0; k < KK; k++) {
                    float d0 = ax - muk[2 * k];
                    float d1 = ay - muk[2 * k + 1];
                    wv[k] = __expf(-0.5f * (d0 * d0 * isgm[2 * k] + d1 * d1 * isgm[2 * k + 1]));
                }
                ua = make_uint4(bfpack(wv[0], wv[1]), bfpack(wv[2], wv[3]),
                                bfpack(wv[4], wv[5]), bfpack(wv[6], wv[7]));
                ub = bfpack(wv[8], wv[9]);
                dp = (int)qv.x;
            }
            *(uint4*)&gws[wave][lane][0] = ua;
            *(uint4*)&gws[wave][lane][4] = make_uint4(ub, 0u, 0u, 0u);
            dposs[wave][lane] = dp;
            __threadfence_block();
            const int ntile = (cnt + 15) >> 4;
            for (int t = 0; t < ntile; t++) {
                short8v A = {0, 0, 0, 0, 0, 0, 0, 0};
                if (q < 2) A = *(const short8v*)&gws[wave][t * 16 + o16][q * 4];
                f32x4 a0 = __builtin_amdgcn_mfma_f32_16x16x32_bf16(A, B0, zacc, 0, 0, 0);
                f32x4 a1 = __builtin_amdgcn_mfma_f32_16x16x32_bf16(A, B1, zacc, 0, 0, 0);
#pragma unroll
                for (int r = 0; r < 4; r++) {
                    int e = t * 16 + 4 * q + r;
                    if (e < cnt) {
                        int dpp = dposs[wave][e];
                        // one uint per lane: cols (o16, o16+16) -> full 64B line/edge
                        m[(size_t)dpp * 16 + o16] = bfpack(a0[r], a1[r]);
                    }
                }
            }
            __threadfence_block();
        }
    }
}

// Phase B: per-dst wave; uint slot p holds cols (p, p+16); fused mean+root+bias+elu
__global__ __launch_bounds__(256) void gather_kernel(const unsigned int* __restrict__ m,
                                                     const int* __restrict__ rpD,
                                                     const float* __restrict__ hxr,
                                                     const float* __restrict__ invdeg,
                                                     const float* __restrict__ b,
                                                     float* __restrict__ out) {
    const int tid = threadIdx.x;
    const int wave = tid >> 6, lane = tid & 63;
    const int p = lane & 15;
    const int h = lane >> 4;
    const int nwaves = gridDim.x * 4;
    const float b0 = b[p], b1 = b[p + 16];
    for (int n = blockIdx.x * 4 + wave; n < NN; n += nwaves) {
        const int s0 = rpD[n], s1 = rpD[n + 1];
        float a0 = 0.0f, a1 = 0.0f;
        for (int s = s0 + h; s < s1; s += 4) {
            unsigned int v = m[(size_t)s * 16 + p];
            a0 += __uint_as_float(v << 16);          // col p
            a1 += __uint_as_float(v & 0xffff0000u);  // col p+16
        }
        a0 += __shfl_xor(a0, 16); a1 += __shfl_xor(a1, 16);
        a0 += __shfl_xor(a0, 32); a1 += __shfl_xor(a1, 32);
        if (h == 0) {
            float inv = invdeg[n];
            float r0 = hxr[(size_t)n * COUT + p];
            float r1 = hxr[(size_t)n * COUT + p + 16];
            float v0 = a0 * inv + r0 + b0;
            float v1 = a1 * inv + r1 + b1;
            v0 = (v0 > 0.0f) ? v0 : (__expf(v0) - 1.0f);
            v1 = (v1 > 0.0f) ? v1 : (__expf(v1) - 1.0f);
            out[(size_t)n * COUT + p] = v0;
            out[(size_t)n * COUT + p + 16] = v1;
        }
    }
}

extern "C" void kernel_launch(void* const* d_in, const int* in_sizes, int n_in,
                              void* d_out, int out_size, void* d_ws, size_t ws_size,
                              hipStream_t stream) {
    const float* graph = (const float*)d_in[0];
    const int* ei = (const int*)d_in[1];
    const float* ea = (const float*)d_in[2];
    const float *G[3], *MU[3], *SG[3], *RT[3], *BB[3];
    for (int l = 0; l < 3; l++) {
        G[l]  = (const float*)d_in[3 + 5 * l + 0];
        MU[l] = (const float*)d_in[3 + 5 * l + 1];
        SG[l] = (const float*)d_in[3 + 5 * l + 2];
        RT[l] = (const float*)d_in[3 + 5 * l + 3];
        BB[l] = (const float*)d_in[3 + 5 * l + 4];
    }
    float* out = (float*)d_out;

    // ---- workspace layout (16B-aligned chunks first) ----
    char* w = (char*)d_ws;
    __hip_bfloat16* hxh = (__hip_bfloat16*)w;   w += (size_t)NN * HCOL * 2;   // 32.0 MB
    float* hxr          = (float*)w;            w += (size_t)NN * COUT * 4;   //  6.4 MB
    unsigned int* m     = (unsigned int*)w;     w += (size_t)NE * 16 * 4;     // 51.2 MB
    uint2* dperm        = (uint2*)w;            w += (size_t)NE * 8;          //  6.4 MB
    ushort2* rankL      = (ushort2*)w;          w += (size_t)NE * 4;          //  3.2 MB
    int* cntS           = (int*)w;              w += (size_t)NREP * NN * 4;
    int* cntD           = (int*)w;              w += (size_t)NREP * NN * 4;   // contiguous with cntS
    float* invdeg       = (float*)w;            w += (size_t)NN * 4;
    int* rpS            = (int*)w;              w += (size_t)(NN + 1) * 4;
    int* rpD            = (int*)w;              w += (size_t)(NN + 1) * 4;
    int* bsumS          = (int*)w;              w += 256 * 4;
    int* bsumD          = (int*)w;              w += 256 * 4;
    int* bposS          = (int*)w;              w += 256 * 4;
    int* bposD          = (int*)w;              w += 256 * 4;

    // ---- CSR build: rank -> scans -> scatter (all solo) ----
    hipMemsetAsync(cntS, 0, 2 * NREP * NN * sizeof(int), stream);
    rank_edges<<<(NE + NREP * 256 - 1) / (NREP * 256), 256, 0, stream>>>(ei, cntS, cntD, rankL);
    scan_partial<<<SCAN_NB, 256, 0, stream>>>(cntS, cntD, bsumS, bsumD);
    scan_blocks<<<1, 256, 0, stream>>>(bsumS, bsumD, bposS, bposD);
    scan_final<<<SCAN_NB, 256, 0, stream>>>(cntS, cntD, bposS, bposD, rpS, rpD, invdeg);
    scatter_perm<<<(NE + 255) / 256, 256, 0, stream>>>(ei, ea, rankL, cntS, cntD, dperm);

    for (int l = 0; l < 3; l++) {
        const float* x = (l == 0) ? graph : (out + (size_t)(l - 1) * NN * COUT);
        if (l == 0)
            gemm_hx64<<<GEMM_NB, 384, 0, stream>>>(x, G[l], RT[l], hxh, hxr);
        else
            gemm_hx32<<<GEMM_NB, 384, 0, stream>>>(x, G[l], RT[l], hxh, hxr);
        msg_kernel<<<2048, 256, 0, stream>>>(hxh, rpS, dperm, MU[l], SG[l], m);
        gather_kernel<<<2048, 256, 0, stream>>>(m, rpD, hxr, invdeg, BB[l],
                                                out + (size_t)l * NN * COUT);
    }
}

// Round 17
// 308.570 us; speedup vs baseline: 1.1648x; 1.1648x over previous
//
#include <hip/hip_runtime.h>
#include <hip/hip_bf16.h>
#include <math.h>

#define NN 50000
#define NE 800000
#define COUT 32
#define KK 10
#define HCOL 320           // K*OUT  (bf16 h panel width, row-major)
#define WCOLS 352          // HCOL + COUT
#define EPSV 1e-15f
#define SCAN_NB 196        // ceil(50000/256)
#define MBATCH 64          // msg edge batch per wave
#define NREP 4             // counter replicas
#define GEMM_NB 782        // ceil(NN / 64)

typedef __attribute__((ext_vector_type(8))) short short8v;   // 8 bf16 (4 VGPR)
typedef __attribute__((ext_vector_type(4))) float f32x4;

__device__ __forceinline__ unsigned int bfpack(float a, float b) {
    // RNE f32->bf16 pair pack (matches __float2bfloat16 for finite values)
    unsigned int ua = __float_as_uint(a), ub = __float_as_uint(b);
    ua = (ua + 0x7fffu + ((ua >> 16) & 1u)) >> 16;
    ub = (ub + 0x7fffu + ((ub >> 16) & 1u)) >> 16;
    return ua | (ub << 16);
}

// ================= CSR build (once per call) =================
// standalone: random-RMW work must not co-run with anything (R13/R14 lessons)
__global__ __launch_bounds__(256) void rank_edges(const int* __restrict__ ei,
                                                  int* __restrict__ cntS,
                                                  int* __restrict__ cntD,
                                                  ushort2* __restrict__ rankL) {
    const int base = blockIdx.x * (NREP * 256);
    const int t = threadIdx.x;
#pragma unroll
    for (int i = 0; i < NREP; i++) {
        int e = base + i * 256 + t;
        if (e < NE) {
            int src = ei[e], dst = ei[NE + e];
            unsigned short rs = (unsigned short)atomicAdd(cntS + i * NN + src, 1);
            unsigned short rd = (unsigned short)atomicAdd(cntD + i * NN + dst, 1);
            rankL[e] = make_ushort2(rs, rd);
        }
    }
}

__device__ __forceinline__ int block_incl_scan(int v, int* s) {
    int t = threadIdx.x;
    s[t] = v; __syncthreads();
#pragma unroll
    for (int off = 1; off < 256; off <<= 1) {
        int u = (t >= off) ? s[t - off] : 0;
        __syncthreads();
        s[t] += u; __syncthreads();
    }
    int r = s[t]; __syncthreads();
    return r;
}

__global__ __launch_bounds__(256) void scan_partial(const int* __restrict__ cntS,
                                                    const int* __restrict__ cntD,
                                                    int* __restrict__ bsumS,
                                                    int* __restrict__ bsumD) {
    __shared__ int s[256];
    int i = blockIdx.x * 256 + threadIdx.x;
    int vs = 0, vd = 0;
    if (i < NN) {
#pragma unroll
        for (int r = 0; r < NREP; r++) {
            vs += cntS[(size_t)r * NN + i];
            vd += cntD[(size_t)r * NN + i];
        }
    }
    int is = block_incl_scan(vs, s);
    int id = block_incl_scan(vd, s);
    if (threadIdx.x == 255) { bsumS[blockIdx.x] = is; bsumD[blockIdx.x] = id; }
}

__global__ __launch_bounds__(256) void scan_blocks(int* __restrict__ bsumS,
                                                   int* __restrict__ bsumD,
                                                   int* __restrict__ bposS,
                                                   int* __restrict__ bposD) {
    __shared__ int s[256];
    int t = threadIdx.x;
    int vs = (t < SCAN_NB) ? bsumS[t] : 0;
    int vd = (t < SCAN_NB) ? bsumD[t] : 0;
    int is = block_incl_scan(vs, s);
    int id = block_incl_scan(vd, s);
    if (t < SCAN_NB) { bposS[t] = is - vs; bposD[t] = id - vd; }
}

__global__ __launch_bounds__(256) void scan_final(int* __restrict__ cntS,
                                                  int* __restrict__ cntD,
                                                  const int* __restrict__ bposS,
                                                  const int* __restrict__ bposD,
                                                  int* __restrict__ rpS,
                                                  int* __restrict__ rpD,
                                                  float* __restrict__ invdeg) {
    __shared__ int s[256];
    int i = blockIdx.x * 256 + threadIdx.x;
    int cs[NREP], cd[NREP];
    int vs = 0, vd = 0;
    if (i < NN) {
#pragma unroll
        for (int r = 0; r < NREP; r++) {
            cs[r] = cntS[(size_t)r * NN + i];
            cd[r] = cntD[(size_t)r * NN + i];
            vs += cs[r]; vd += cd[r];
        }
    }
    int is = block_incl_scan(vs, s);
    int id = block_incl_scan(vd, s);
    if (i < NN) {
        int es = bposS[blockIdx.x] + is - vs;
        int ed = bposD[blockIdx.x] + id - vd;
        rpS[i] = es; rpD[i] = ed;
        invdeg[i] = 1.0f / fmaxf((float)vd, 1.0f);
        int run = es;
#pragma unroll
        for (int r = 0; r < NREP; r++) { cntS[(size_t)r * NN + i] = run; run += cs[r]; }
        run = ed;
#pragma unroll
        for (int r = 0; r < NREP; r++) { cntD[(size_t)r * NN + i] = run; run += cd[r]; }
    }
    if (i == NN) { rpS[NN] = NE; rpD[NN] = NE; }
}

// atomic-free permutation scatter: one aligned 8B store per edge {dslot, bf16 ea pair}
__global__ void scatter_perm(const int* __restrict__ ei, const float* __restrict__ ea,
                             const ushort2* __restrict__ rankL,
                             const int* __restrict__ cntS, const int* __restrict__ cntD,
                             uint2* __restrict__ dperm) {
    int e = blockIdx.x * 256 + threadIdx.x;
    if (e >= NE) return;
    int src = ei[e], dst = ei[NE + e];
    int rep = (e >> 8) & (NREP - 1);        // matches rank_edges' slot layout
    ushort2 rl = rankL[e];
    int sslot = cntS[(size_t)rep * NN + src] + rl.x;
    int dslot = cntD[(size_t)rep * NN + dst] + rl.y;
    float2 a = ((const float2*)ea)[e];
    dperm[sslot] = make_uint2((unsigned int)dslot, bfpack(a.x, a.y));
}

// ================= per-layer kernels =================

// W panel transpose+bf16 convert (once per layer, tiny): Wtg[j][c] = [g|root][c][j]
template <int CIN>
__global__ void wcvt(const float* __restrict__ g, const float* __restrict__ root,
                     __hip_bfloat16* __restrict__ Wtg) {
    int idx = blockIdx.x * 256 + threadIdx.x;
    if (idx >= WCOLS * CIN) return;
    int j = idx / CIN, c = idx % CIN;
    float v = (j < HCOL) ? g[(size_t)c * HCOL + j] : root[(size_t)c * COUT + (j - HCOL)];
    Wtg[idx] = __float2bfloat16(v);
}

// MFMA feature GEMM: hx = x @ [g | root], 64 rows/block, 4 waves, 22 N-tiles.
// Same consistent-k-map trick as msg_kernel (HW-validated R11/R12): A lane holds
// row (lane&15), k-slot 8q+i; B lane holds col (lane&15), same slots; C layout
// col=lane&15, row=4q+reg (m89). h cols -> bf16 hxh, root cols -> fp32 hxr.
template <int CIN>
__global__ __launch_bounds__(256) void gemm_mfma(const float* __restrict__ x,
                                                 const __hip_bfloat16* __restrict__ Wtg,
                                                 __hip_bfloat16* __restrict__ hxh,
                                                 float* __restrict__ hxr) {
    constexpr int KST = CIN / 32;
    constexpr int LDW = CIN + 8;
    __shared__ __hip_bfloat16 xs[64][LDW];
    __shared__ __hip_bfloat16 wt[WCOLS][LDW];
    const int tid = threadIdx.x;
    const int n0 = blockIdx.x * 64;
    // stage x (fp32 -> bf16), 8 elems/iter, coalesced
    for (int idx = tid; idx < 64 * CIN / 8; idx += 256) {
        int i = (idx * 8) / CIN, c0 = (idx * 8) % CIN;
        int n = n0 + i;
        uint4 u = make_uint4(0u, 0u, 0u, 0u);
        if (n < NN) {
            float4 f0 = *(const float4*)&x[(size_t)n * CIN + c0];
            float4 f1 = *(const float4*)&x[(size_t)n * CIN + c0 + 4];
            u = make_uint4(bfpack(f0.x, f0.y), bfpack(f0.z, f0.w),
                           bfpack(f1.x, f1.y), bfpack(f1.z, f1.w));
        }
        *(uint4*)&xs[i][c0] = u;
    }
    // stage Wt (already bf16, row-major [352][CIN]), coalesced 16B copies
    for (int idx = tid; idx < WCOLS * CIN / 8; idx += 256) {
        int j = (idx * 8) / CIN, c0 = (idx * 8) % CIN;
        *(uint4*)&wt[j][c0] = *(const uint4*)&Wtg[(size_t)j * CIN + c0];
    }
    __syncthreads();
    const int wv = tid >> 6, ln = tid & 63, p = ln & 15, q = ln >> 4;
    const int rbase = 16 * wv;
    short8v A[KST];
#pragma unroll
    for (int s = 0; s < KST; s++)
        A[s] = *(const short8v*)&xs[rbase + p][32 * s + 8 * q];
    const f32x4 z = {0.0f, 0.0f, 0.0f, 0.0f};
    for (int t = 0; t < 22; t++) {
        f32x4 acc = z;
#pragma unroll
        for (int s = 0; s < KST; s++) {
            short8v B = *(const short8v*)&wt[16 * t + p][32 * s + 8 * q];
            acc = __builtin_amdgcn_mfma_f32_16x16x32_bf16(A[s], B, acc, 0, 0, 0);
        }
        const int j = 16 * t + p;
#pragma unroll
        for (int r = 0; r < 4; r++) {
            int n = n0 + rbase + 4 * q + r;
            if (n < NN) {
                if (t < 20) hxh[(size_t)n * HCOL + j] = __float2bfloat16(acc[r]);
                else        hxr[(size_t)n * COUT + (j - HCOL)] = acc[r];
            }
        }
    }
}

// Phase A (MFMA): per-src wave; phase1 one lane/edge -> 10 gaussians into LDS;
// phase2 16-edge x 32-out tiles via two mfma_f32_16x16x32_bf16.
// m-row layout COLUMN-INTERLEAVED: uint slot j holds cols (j, j+16) packed.
__global__ __launch_bounds__(256) void msg_kernel(const __hip_bfloat16* __restrict__ hxh,
                                                  const int* __restrict__ rpS,
                                                  const uint2* __restrict__ dperm,
                                                  const float* __restrict__ mu,
                                                  const float* __restrict__ sigma,
                                                  unsigned int* __restrict__ m) {
    __shared__ unsigned int gws[4][MBATCH][8];   // 8 KB: [wave][edge][16 khat bf16]
    __shared__ int dposs[4][MBATCH];             // 1 KB
    float muk[2 * KK], isgm[2 * KK];
#pragma unroll
    for (int k = 0; k < 2 * KK; k++) {
        muk[k] = mu[k];
        float sv = sigma[k];
        isgm[k] = 1.0f / (EPSV + sv * sv);
    }
    const int tid = threadIdx.x;
    const int wave = tid >> 6, lane = tid & 63;
    const int o16 = lane & 15, q = lane >> 4;
    const int nwaves = gridDim.x * 4;
    const f32x4 zacc = {0.0f, 0.0f, 0.0f, 0.0f};
    for (int n = blockIdx.x * 4 + wave; n < NN; n += nwaves) {
        const int s0 = rpS[n], s1 = rpS[n + 1];
        if (s0 == s1) continue;
        short8v B0 = {0, 0, 0, 0, 0, 0, 0, 0};
        short8v B1 = {0, 0, 0, 0, 0, 0, 0, 0};
        if (q < 2) {                         // khat 0..15 live; 16..31 zero
            const short* hr = (const short*)(hxh + (size_t)n * HCOL);
#pragma unroll
            for (int i = 0; i < 8; i++) {
                int k = q * 8 + i;
                int kc = (k < KK) ? k : (KK - 1);     // clamped (in-bounds) address
                short v0 = hr[kc * 32 + o16];
                short v1 = hr[kc * 32 + 16 + o16];
                B0[i] = (k < KK) ? v0 : (short)0;
                B1[i] = (k < KK) ? v1 : (short)0;
            }
        }
        for (int base = s0; base < s1; base += MBATCH) {
            const int cnt = min(MBATCH, s1 - base);
            uint4 ua = make_uint4(0u, 0u, 0u, 0u);
            unsigned int ub = 0u; int dp = 0;
            if (lane < cnt) {                // phase 1: one edge per lane
                uint2 qv = dperm[base + lane];
                float ax = __uint_as_float(qv.y << 16);
                float ay = __uint_as_float(qv.y & 0xffff0000u);
                float wv[KK];
#pragma unroll
                for (int k = 0; k < KK; k++) {
                    float d0 = ax - muk[2 * k];
                    float d1 = ay - muk[2 * k + 1];
                    wv[k] = __expf(-0.5f * (d0 * d0 * isgm[2 * k] + d1 * d1 * isgm[2 * k + 1]));
                }
                ua = make_uint4(bfpack(wv[0], wv[1]), bfpack(wv[2], wv[3]),
                                bfpack(wv[4], wv[5]), bfpack(wv[6], wv[7]));
                ub = bfpack(wv[8], wv[9]);
                dp = (int)qv.x;
            }
            *(uint4*)&gws[wave][lane][0] = ua;
            *(uint4*)&gws[wave][lane][4] = make_uint4(ub, 0u, 0u, 0u);
            dposs[wave][lane] = dp;
            __threadfence_block();
            const int ntile = (cnt + 15) >> 4;
            for (int t = 0; t < ntile; t++) {
                short8v A = {0, 0, 0, 0, 0, 0, 0, 0};
                if (q < 2) A = *(const short8v*)&gws[wave][t * 16 + o16][q * 4];
                f32x4 a0 = __builtin_amdgcn_mfma_f32_16x16x32_bf16(A, B0, zacc, 0, 0, 0);
                f32x4 a1 = __builtin_amdgcn_mfma_f32_16x16x32_bf16(A, B1, zacc, 0, 0, 0);
#pragma unroll
                for (int r = 0; r < 4; r++) {
                    int e = t * 16 + 4 * q + r;
                    if (e < cnt) {
                        int dpp = dposs[wave][e];
                        m[(size_t)dpp * 16 + o16] = bfpack(a0[r], a1[r]);
                    }
                }
            }
            __threadfence_block();
        }
    }
}

// Phase B: per-dst wave; uint slot p holds cols (p, p+16); fused mean+root+bias+elu
__global__ __launch_bounds__(256) void gather_kernel(const unsigned int* __restrict__ m,
                                                     const int* __restrict__ rpD,
                                                     const float* __restrict__ hxr,
                                                     const float* __restrict__ invdeg,
                                                     const float* __restrict__ b,
                                                     float* __restrict__ out) {
    const int tid = threadIdx.x;
    const int wave = tid >> 6, lane = tid & 63;
    const int p = lane & 15;
    const int h = lane >> 4;
    const int nwaves = gridDim.x * 4;
    const float b0 = b[p], b1 = b[p + 16];
    for (int n = blockIdx.x * 4 + wave; n < NN; n += nwaves) {
        const int s0 = rpD[n], s1 = rpD[n + 1];
        float a0 = 0.0f, a1 = 0.0f;
        for (int s = s0 + h; s < s1; s += 4) {
            unsigned int v = m[(size_t)s * 16 + p];
            a0 += __uint_as_float(v << 16);          // col p
            a1 += __uint_as_float(v & 0xffff0000u);  // col p+16
        }
        a0 += __shfl_xor(a0, 16); a1 += __shfl_xor(a1, 16);
        a0 += __shfl_xor(a0, 32); a1 += __shfl_xor(a1, 32);
        if (h == 0) {
            float inv = invdeg[n];
            float r0 = hxr[(size_t)n * COUT + p];
            float r1 = hxr[(size_t)n * COUT + p + 16];
            float v0 = a0 * inv + r0 + b0;
            float v1 = a1 * inv + r1 + b1;
            v0 = (v0 > 0.0f) ? v0 : (__expf(v0) - 1.0f);
            v1 = (v1 > 0.0f) ? v1 : (__expf(v1) - 1.0f);
            out[(size_t)n * COUT + p] = v0;
            out[(size_t)n * COUT + p + 16] = v1;
        }
    }
}

extern "C" void kernel_launch(void* const* d_in, const int* in_sizes, int n_in,
                              void* d_out, int out_size, void* d_ws, size_t ws_size,
                              hipStream_t stream) {
    const float* graph = (const float*)d_in[0];
    const int* ei = (const int*)d_in[1];
    const float* ea = (const float*)d_in[2];
    const float *G[3], *MU[3], *SG[3], *RT[3], *BB[3];
    for (int l = 0; l < 3; l++) {
        G[l]  = (const float*)d_in[3 + 5 * l + 0];
        MU[l] = (const float*)d_in[3 + 5 * l + 1];
        SG[l] = (const float*)d_in[3 + 5 * l + 2];
        RT[l] = (const float*)d_in[3 + 5 * l + 3];
        BB[l] = (const float*)d_in[3 + 5 * l + 4];
    }
    float* out = (float*)d_out;

    // ---- workspace layout (16B-aligned chunks first) ----
    char* w = (char*)d_ws;
    __hip_bfloat16* hxh = (__hip_bfloat16*)w;   w += (size_t)NN * HCOL * 2;   // 32.0 MB
    float* hxr          = (float*)w;            w += (size_t)NN * COUT * 4;   //  6.4 MB
    unsigned int* m     = (unsigned int*)w;     w += (size_t)NE * 16 * 4;     // 51.2 MB
    uint2* dperm        = (uint2*)w;            w += (size_t)NE * 8;          //  6.4 MB
    ushort2* rankL      = (ushort2*)w;          w += (size_t)NE * 4;          //  3.2 MB
    __hip_bfloat16* Wtg = (__hip_bfloat16*)w;   w += (size_t)WCOLS * 64 * 2;  // 45 KB
    int* cntS           = (int*)w;              w += (size_t)NREP * NN * 4;
    int* cntD           = (int*)w;              w += (size_t)NREP * NN * 4;   // contiguous with cntS
    float* invdeg       = (float*)w;            w += (size_t)NN * 4;
    int* rpS            = (int*)w;              w += (size_t)(NN + 1) * 4;
    int* rpD            = (int*)w;              w += (size_t)(NN + 1) * 4;
    int* bsumS          = (int*)w;              w += 256 * 4;
    int* bsumD          = (int*)w;              w += 256 * 4;
    int* bposS          = (int*)w;              w += 256 * 4;
    int* bposD          = (int*)w;              w += 256 * 4;

    // ---- CSR build: rank -> scans -> scatter (all solo) ----
    hipMemsetAsync(cntS, 0, 2 * NREP * NN * sizeof(int), stream);
    rank_edges<<<(NE + NREP * 256 - 1) / (NREP * 256), 256, 0, stream>>>(ei, cntS, cntD, rankL);
    scan_partial<<<SCAN_NB, 256, 0, stream>>>(cntS, cntD, bsumS, bsumD);
    scan_blocks<<<1, 256, 0, stream>>>(bsumS, bsumD, bposS, bposD);
    scan_final<<<SCAN_NB, 256, 0, stream>>>(cntS, cntD, bposS, bposD, rpS, rpD, invdeg);
    scatter_perm<<<(NE + 255) / 256, 256, 0, stream>>>(ei, ea, rankL, cntS, cntD, dperm);

    for (int l = 0; l < 3; l++) {
        const float* x = (l == 0) ? graph : (out + (size_t)(l - 1) * NN * COUT);
        if (l == 0) {
            wcvt<64><<<(WCOLS * 64 + 255) / 256, 256, 0, stream>>>(G[l], RT[l], Wtg);
            gemm_mfma<64><<<GEMM_NB, 256, 0, stream>>>(x, Wtg, hxh, hxr);
        } else {
            wcvt<32><<<(WCOLS * 32 + 255) / 256, 256, 0, stream>>>(G[l], RT[l], Wtg);
            gemm_mfma<32><<<GEMM_NB, 256, 0, stream>>>(x, Wtg, hxh, hxr);
        }
        msg_kernel<<<2048, 256, 0, stream>>>(hxh, rpS, dperm, MU[l], SG[l], m);
        gather_kernel<<<2048, 256, 0, stream>>>(m, rpD, hxr, invdeg, BB[l],
                                                out + (size_t)l * NN * COUT);
    }
}